// Round 9
// baseline (152.954 us; speedup 1.0000x reference)
//
#include <hip/hip_runtime.h>
#include <math.h>

// MultiHeadAttention_3728031613617 — bf16-MFMA pipeline v9.
// v9 flash: Q-tile 16, block 512 (8-wave K-split), grid 1024 = 32 waves/CU
// (max occupancy; LDS exactly 40960 B x 4 blocks/CU). K fragments loaded
// DIRECT from global (coalesced B-frag layout — r4 address-math re-derived),
// V staged in wave-private LDS, P in its own de-aliased 1KB region.
// Coalesced OutS dense tail from r8 (WRITE_SIZE-verified).

typedef __bf16 bf16;
typedef __bf16 bf16x4v __attribute__((ext_vector_type(4)));
typedef __bf16 bf16x8v __attribute__((ext_vector_type(8)));
typedef float f32x4 __attribute__((ext_vector_type(4)));

namespace {
constexpr int kS = 2048;
constexpr int kD = 512;
constexpr int kRows = 16384;  // 8 * 2048
}

#define MFMA16(a, b, c) __builtin_amdgcn_mfma_f32_16x16x32_bf16((a), (b), (c), 0, 0, 0)

// ---------------------------------------------------------------------------
// Kernel 0: prep. wtg[mat][n=64][k=512] = (bf16)W[mat][k][n]
//           drt[o=512][j=64] = (bf16) sum_h dense[h*64+j, o]  (for B-frags)
// ---------------------------------------------------------------------------
__global__ __launch_bounds__(256) void prep_kernel(const float* __restrict__ w,
                                                   const float* __restrict__ dense,
                                                   bf16* __restrict__ wtg,
                                                   bf16* __restrict__ drt) {
  int idx = blockIdx.x * 256 + threadIdx.x;  // < 131072
  if (idx < 98304) {
    int mat = idx >> 15, rem = idx & 32767;
    int n = rem >> 9, k = rem & 511;
    wtg[idx] = (bf16)w[mat * 32768 + k * 64 + n];
  } else {
    int e = idx - 98304;  // < 32768
    int o = e >> 6, j = e & 63;
    float s = 0.f;
#pragma unroll
    for (int h = 0; h < 8; ++h) s += dense[(size_t)(h * 64 + j) * kD + o];
    drt[e] = (bf16)s;  // [o][j]
  }
}

// ---------------------------------------------------------------------------
// Kernel 1: fused QKV projection (x read ONCE). grid 256, block 256. (v6)
// ---------------------------------------------------------------------------
__global__ __launch_bounds__(256) void proj_kernel(const float* __restrict__ x,
                                                   const bf16* __restrict__ wtg,
                                                   bf16* __restrict__ wq,
                                                   bf16* __restrict__ wk,
                                                   bf16* __restrict__ wvt) {
  const int bt = blockIdx.x;
  const int tid = threadIdx.x;
  const int w = tid >> 6, tx = tid & 15, quad = (tid >> 4) & 3;
  const int row0 = bt * 64;

  __shared__ bf16 Xs[64 * 72];
  __shared__ bf16 Wts[3 * 64 * 72];

  f32x4 acc[3][4];
#pragma unroll
  for (int m = 0; m < 3; ++m)
#pragma unroll
    for (int nt = 0; nt < 4; ++nt) acc[m][nt] = (f32x4){0.f, 0.f, 0.f, 0.f};

  for (int k0 = 0; k0 < kD; k0 += 64) {
    __syncthreads();
#pragma unroll
    for (int p = 0; p < 4; ++p) {
      int i4 = tid + p * 256;
      int r = i4 >> 4, c4 = (i4 & 15) * 4;
      float4 f = *(const float4*)&x[(size_t)(row0 + r) * kD + k0 + c4];
      bf16x4v h = {(bf16)f.x, (bf16)f.y, (bf16)f.z, (bf16)f.w};
      *(bf16x4v*)&Xs[r * 72 + c4] = h;
    }
#pragma unroll
    for (int p = 0; p < 6; ++p) {
      int cc = tid + p * 256;
      int mat = cc >> 9, rem = cc & 511;
      int n = rem >> 3, c8 = (rem & 7) * 8;
      *(uint4*)&Wts[(mat * 64 + n) * 72 + c8] =
          *(const uint4*)&wtg[(size_t)mat * 32768 + (size_t)n * 512 + k0 + c8];
    }
    __syncthreads();
#pragma unroll
    for (int s = 0; s < 2; ++s) {
      bf16x8v a = *(bf16x8v*)&Xs[(w * 16 + tx) * 72 + s * 32 + quad * 8];
#pragma unroll
      for (int m = 0; m < 3; ++m)
#pragma unroll
        for (int nt = 0; nt < 4; ++nt) {
          bf16x8v bfr =
              *(bf16x8v*)&Wts[(m * 64 + nt * 16 + tx) * 72 + s * 32 + quad * 8];
          acc[m][nt] = MFMA16(a, bfr, acc[m][nt]);
        }
    }
  }

#pragma unroll
  for (int nt = 0; nt < 4; ++nt)
#pragma unroll
    for (int r = 0; r < 4; ++r) {
      int row_g = row0 + w * 16 + quad * 4 + r;
      int col = nt * 16 + tx;
      wq[(size_t)row_g * 64 + col] = (bf16)acc[0][nt][r];
      wk[(size_t)row_g * 64 + col] = (bf16)acc[1][nt][r];
    }
  __syncthreads();
  bf16* Vt = Xs;
#pragma unroll
  for (int nt = 0; nt < 4; ++nt)
#pragma unroll
    for (int r = 0; r < 4; ++r)
      Vt[(nt * 16 + tx) * 72 + (w * 16 + quad * 4 + r)] = (bf16)acc[2][nt][r];
  __syncthreads();
#pragma unroll
  for (int p = 0; p < 2; ++p) {
    int c = tid + p * 256;
    int v = c >> 3, seg = c & 7;
    *(uint4*)&wvt[(size_t)v * kRows + row0 + seg * 8] =
        *(uint4*)&Vt[v * 72 + seg * 8];
  }
}

// ---------------------------------------------------------------------------
// Kernel 2: flash attention v9.
// grid 1024: b = bid&7 (XCD affinity), qb = bid>>3 (16 Q-rows). Block 512 =
// 8 waves; wave w owns key tiles (t*8+w)*32, t<8. Barrier-free main loop.
// LDS map (40960 B total -> 4 blocks/CU = 32 waves/CU):
//   slot[w] = lds + w*5120:  V 64x32 bf16 swizzled @0 (4KB), P 16x32 @4096 (1KB)
//   combine: myO[w] 16x64 f32 aliases slot V region (4KB)
//   Lsh (128 f32)  @ slot5 P region (29696)
//   vob rows 0-7   @ slot6 P region (34816), rows 8-15 @ slot7 P (39936)
//   OutS 16x260 f32 @0 (16640 B, aliases dead slots 0-3)
// ---------------------------------------------------------------------------
__global__ __launch_bounds__(512, 8) void flash_kernel(
    const bf16* __restrict__ wq, const bf16* __restrict__ wk,
    const bf16* __restrict__ wvt, const bf16* __restrict__ drt,
    float* __restrict__ out) {
  const int bid = blockIdx.x;
  const int b = bid & 7, qb = bid >> 3;
  const int q0 = qb * 16;
  const int tid = threadIdx.x;
  const int w = tid >> 6, lane = tid & 63, tx = tid & 15, quad = (tid >> 4) & 3;

  __shared__ __align__(16) char lds[40960];
  bf16* Vtw = (bf16*)(lds + w * 5120);         // 64 v x 32 keys (swizzled)
  bf16* Psw = (bf16*)(lds + w * 5120 + 4096);  // 16 q x 32 keys (swizzled)

  const bf16* wqb = wq + (size_t)(b * kS) * 64;
  const bf16* wkb = wk + (size_t)(b * kS) * 64;
  const bf16* wvb = wvt + b * kS;

  const int kc0 = (quad ^ (tx & 7)) * 8;        // 64-wide swizzled rows, s=0
  const int kc1 = ((4 + quad) ^ (tx & 7)) * 8;  // s=1
  const int h2 = (tx ^ (tx >> 2)) & 3;          // 32-wide rows keyed by tx

  // Q fragments: loop-invariant, direct from global
  bf16x8v aq0 = *(const bf16x8v*)&wqb[(size_t)(q0 + tx) * 64 + quad * 8];
  bf16x8v aq1 = *(const bf16x8v*)&wqb[(size_t)(q0 + tx) * 64 + 32 + quad * 8];

  f32x4 oacc[4];
#pragma unroll
  for (int nt = 0; nt < 4; ++nt) oacc[nt] = (f32x4){0.f, 0.f, 0.f, 0.f};
  float lsum[4] = {0.f, 0.f, 0.f, 0.f};

  const int vsv = lane >> 2, vsck = lane & 3;  // V staging: 4 lanes/v-row

  for (int t = 0; t < 8; ++t) {
    const int k0 = (t * 8 + w) * 32;
    // V: global -> wave-private swizzled LDS (issued first)
#pragma unroll
    for (int j = 0; j < 4; ++j) {
      int v = vsv + j * 16;
      *(uint4*)&Vtw[v * 32 + ((vsck ^ ((v ^ (v >> 2)) & 3)) * 8)] =
          *(const uint4*)&wvb[(size_t)v * kRows + k0 + vsck * 8];
    }
    // K fragments: DIRECT from global (coalesced 16x64B row segments)
    bf16x8v kb[2][2];
#pragma unroll
    for (int nt = 0; nt < 2; ++nt) {
      kb[nt][0] =
          *(const bf16x8v*)&wkb[(size_t)(k0 + nt * 16 + tx) * 64 + quad * 8];
      kb[nt][1] = *(const bf16x8v*)&wkb[(size_t)(k0 + nt * 16 + tx) * 64 + 32 +
                                        quad * 8];
    }

    // QK^T + no-max softmax numerator + swizzled P store (C -> A layout)
#pragma unroll
    for (int nt = 0; nt < 2; ++nt) {
      f32x4 z = (f32x4){0.f, 0.f, 0.f, 0.f};
      z = MFMA16(aq0, kb[nt][0], z);
      z = MFMA16(aq1, kb[nt][1], z);
#pragma unroll
      for (int r = 0; r < 4; ++r) {
        float p = __expf(z[r] * 0.1f);
        lsum[r] += p;
        int q = quad * 4 + r;
        int chunk = nt * 2 + (tx >> 3);
        Psw[q * 32 + ((chunk ^ (r ^ quad)) * 8) + (tx & 7)] = (bf16)p;
      }
    }

    // PV: O[16 q][64 v] += P[16][32] * V[32][64]
    bf16x8v pa = *(bf16x8v*)&Psw[tx * 32 + ((quad ^ h2) * 8)];
#pragma unroll
    for (int nt = 0; nt < 4; ++nt) {
      bf16x8v vb = *(bf16x8v*)&Vtw[(nt * 16 + tx) * 32 + ((quad ^ h2) * 8)];
      oacc[nt] = MFMA16(pa, vb, oacc[nt]);
    }
  }

  // ---- cross-wave combine ----
  __syncthreads();
  float* myO = (float*)(lds + w * 5120);       // 16 x 64 f32 (slot V region)
  float* Lsh = (float*)(lds + 29696);          // 8 waves x 16 rows
#pragma unroll
  for (int nt = 0; nt < 4; ++nt)
#pragma unroll
    for (int r = 0; r < 4; ++r)
      myO[(quad * 4 + r) * 64 + nt * 16 + tx] = oacc[nt][r];
#pragma unroll
  for (int r = 0; r < 4; ++r) {
    float v = lsum[r];
#pragma unroll
    for (int m = 1; m < 16; m <<= 1) v += __shfl_xor(v, m, 64);
    if (tx == 0) Lsh[w * 16 + quad * 4 + r] = v;
  }
  __syncthreads();

  // combined normalized O -> vob (bf16, row-swizzled, split across slot6/7 P)
#pragma unroll
  for (int p = 0; p < 2; ++p) {
    int e = tid + p * 512;  // 1024: 16 rows x 64 cols
    int row = e >> 6, col = e & 63;
    float s = 0.f, lt = 0.f;
#pragma unroll
    for (int wv = 0; wv < 8; ++wv) {
      s += ((const float*)(lds + wv * 5120))[e];
      lt += Lsh[wv * 16 + row];
    }
    bf16* vbase = (bf16*)(lds + ((row < 8) ? 34816 : 39936));
    vbase[(row & 7) * 64 + (((col >> 3) ^ (row & 7)) * 8) + (col & 7)] =
        (bf16)(s / lt);
  }
  __syncthreads();

  // ---- fused dense epilogue: out[16 x 512] = vob[16 x 64] @ drt^T ----
  const bf16* vbase = (const bf16*)(lds + ((tx < 8) ? 34816 : 39936)) +
                      (size_t)(tx & 7) * 64;
  bf16x8v av0 = *(const bf16x8v*)&vbase[kc0];
  bf16x8v av1 = *(const bf16x8v*)&vbase[kc1];

  float* OutS = (float*)lds;  // 16 x 260 f32 = 16640 B (dead slots 0-3)
#pragma unroll
  for (int c = 0; c < 2; ++c) {  // two 256-col chunks
    if (c) __syncthreads();      // prior chunk's OutS reads done
#pragma unroll
    for (int i = 0; i < 2; ++i) {
      const int ct = c * 16 + w * 2 + i;  // global 16-col tile
      bf16x8v bd0 =
          *(const bf16x8v*)&drt[(size_t)(ct * 16 + tx) * 64 + quad * 8];
      bf16x8v bd1 =
          *(const bf16x8v*)&drt[(size_t)(ct * 16 + tx) * 64 + 32 + quad * 8];
      f32x4 z = (f32x4){0.f, 0.f, 0.f, 0.f};
      z = MFMA16(av0, bd0, z);
      z = MFMA16(av1, bd1, z);
#pragma unroll
      for (int r = 0; r < 4; ++r)
        OutS[(quad * 4 + r) * 260 + (w * 2 + i) * 16 + tx] = z[r];
    }
    __syncthreads();
    // coalesced full-row stores: 16 rows x 256 f32 = 1KB contiguous per row
#pragma unroll
    for (int p = 0; p < 2; ++p) {
      int e = tid + p * 512;  // 1024 float4: 16 rows x 64 segs
      int row = e >> 6, seg = e & 63;
      *(float4*)&out[(size_t)(b * kS + q0 + row) * kD + c * 256 + seg * 4] =
          *(float4*)&OutS[row * 260 + seg * 4];
    }
  }
}

extern "C" void kernel_launch(void* const* d_in, const int* in_sizes, int n_in,
                              void* d_out, int out_size, void* d_ws,
                              size_t ws_size, hipStream_t stream) {
  const float* x = (const float*)d_in[0];      // [8,2048,512]
  const float* w = (const float*)d_in[1];      // [3,512,64]
  const float* dense = (const float*)d_in[2];  // [512,512]
  float* out = (float*)d_out;                  // [8,2048,512] fp32

  bf16* wq = (bf16*)d_ws;                // 1,048,576 bf16
  bf16* wk = wq + (size_t)kRows * 64;    // 1,048,576
  bf16* wvt = wk + (size_t)kRows * 64;   // 1,048,576  [64][16384]
  bf16* wtg = wvt + (size_t)kRows * 64;  // 98,304     [3][64][512]
  bf16* drt = wtg + 98304;               // 32,768     [512][64]

  prep_kernel<<<512, 256, 0, stream>>>(w, dense, wtg, drt);
  proj_kernel<<<256, 256, 0, stream>>>(x, wtg, wq, wk, wvt);
  flash_kernel<<<1024, 512, 0, stream>>>(wq, wk, wvt, drt, out);
}

// Round 10
// 149.263 us; speedup vs baseline: 1.0247x; 1.0247x over previous
//
#include <hip/hip_runtime.h>
#include <math.h>

// MultiHeadAttention_3728031613617 — bf16-MFMA pipeline v10.
// v10 = v9 with ONE change: __launch_bounds__(512,8) -> (512,4).
// r9's VGPR_Count=32 proved the 8-waves/EU bound forced spill-to-scratch
// (WRITE_SIZE +12MB, MfmaUtil down); at cap 128 the kernel's natural ~64
// VGPRs still allow 8 waves/EU by HW occupancy rules, LDS (40960 B) still
// allows 4 blocks/CU — intended 32 waves/CU without the spill tax.

typedef __bf16 bf16;
typedef __bf16 bf16x4v __attribute__((ext_vector_type(4)));
typedef __bf16 bf16x8v __attribute__((ext_vector_type(8)));
typedef float f32x4 __attribute__((ext_vector_type(4)));

namespace {
constexpr int kS = 2048;
constexpr int kD = 512;
constexpr int kRows = 16384;  // 8 * 2048
}

#define MFMA16(a, b, c) __builtin_amdgcn_mfma_f32_16x16x32_bf16((a), (b), (c), 0, 0, 0)

// ---------------------------------------------------------------------------
// Kernel 0: prep. wtg[mat][n=64][k=512] = (bf16)W[mat][k][n]
//           drt[o=512][j=64] = (bf16) sum_h dense[h*64+j, o]  (for B-frags)
// ---------------------------------------------------------------------------
__global__ __launch_bounds__(256) void prep_kernel(const float* __restrict__ w,
                                                   const float* __restrict__ dense,
                                                   bf16* __restrict__ wtg,
                                                   bf16* __restrict__ drt) {
  int idx = blockIdx.x * 256 + threadIdx.x;  // < 131072
  if (idx < 98304) {
    int mat = idx >> 15, rem = idx & 32767;
    int n = rem >> 9, k = rem & 511;
    wtg[idx] = (bf16)w[mat * 32768 + k * 64 + n];
  } else {
    int e = idx - 98304;  // < 32768
    int o = e >> 6, j = e & 63;
    float s = 0.f;
#pragma unroll
    for (int h = 0; h < 8; ++h) s += dense[(size_t)(h * 64 + j) * kD + o];
    drt[e] = (bf16)s;  // [o][j]
  }
}

// ---------------------------------------------------------------------------
// Kernel 1: fused QKV projection (x read ONCE). grid 256, block 256. (v6)
// ---------------------------------------------------------------------------
__global__ __launch_bounds__(256) void proj_kernel(const float* __restrict__ x,
                                                   const bf16* __restrict__ wtg,
                                                   bf16* __restrict__ wq,
                                                   bf16* __restrict__ wk,
                                                   bf16* __restrict__ wvt) {
  const int bt = blockIdx.x;
  const int tid = threadIdx.x;
  const int w = tid >> 6, tx = tid & 15, quad = (tid >> 4) & 3;
  const int row0 = bt * 64;

  __shared__ bf16 Xs[64 * 72];
  __shared__ bf16 Wts[3 * 64 * 72];

  f32x4 acc[3][4];
#pragma unroll
  for (int m = 0; m < 3; ++m)
#pragma unroll
    for (int nt = 0; nt < 4; ++nt) acc[m][nt] = (f32x4){0.f, 0.f, 0.f, 0.f};

  for (int k0 = 0; k0 < kD; k0 += 64) {
    __syncthreads();
#pragma unroll
    for (int p = 0; p < 4; ++p) {
      int i4 = tid + p * 256;
      int r = i4 >> 4, c4 = (i4 & 15) * 4;
      float4 f = *(const float4*)&x[(size_t)(row0 + r) * kD + k0 + c4];
      bf16x4v h = {(bf16)f.x, (bf16)f.y, (bf16)f.z, (bf16)f.w};
      *(bf16x4v*)&Xs[r * 72 + c4] = h;
    }
#pragma unroll
    for (int p = 0; p < 6; ++p) {
      int cc = tid + p * 256;
      int mat = cc >> 9, rem = cc & 511;
      int n = rem >> 3, c8 = (rem & 7) * 8;
      *(uint4*)&Wts[(mat * 64 + n) * 72 + c8] =
          *(const uint4*)&wtg[(size_t)mat * 32768 + (size_t)n * 512 + k0 + c8];
    }
    __syncthreads();
#pragma unroll
    for (int s = 0; s < 2; ++s) {
      bf16x8v a = *(bf16x8v*)&Xs[(w * 16 + tx) * 72 + s * 32 + quad * 8];
#pragma unroll
      for (int m = 0; m < 3; ++m)
#pragma unroll
        for (int nt = 0; nt < 4; ++nt) {
          bf16x8v bfr =
              *(bf16x8v*)&Wts[(m * 64 + nt * 16 + tx) * 72 + s * 32 + quad * 8];
          acc[m][nt] = MFMA16(a, bfr, acc[m][nt]);
        }
    }
  }

#pragma unroll
  for (int nt = 0; nt < 4; ++nt)
#pragma unroll
    for (int r = 0; r < 4; ++r) {
      int row_g = row0 + w * 16 + quad * 4 + r;
      int col = nt * 16 + tx;
      wq[(size_t)row_g * 64 + col] = (bf16)acc[0][nt][r];
      wk[(size_t)row_g * 64 + col] = (bf16)acc[1][nt][r];
    }
  __syncthreads();
  bf16* Vt = Xs;
#pragma unroll
  for (int nt = 0; nt < 4; ++nt)
#pragma unroll
    for (int r = 0; r < 4; ++r)
      Vt[(nt * 16 + tx) * 72 + (w * 16 + quad * 4 + r)] = (bf16)acc[2][nt][r];
  __syncthreads();
#pragma unroll
  for (int p = 0; p < 2; ++p) {
    int c = tid + p * 256;
    int v = c >> 3, seg = c & 7;
    *(uint4*)&wvt[(size_t)v * kRows + row0 + seg * 8] =
        *(uint4*)&Vt[v * 72 + seg * 8];
  }
}

// ---------------------------------------------------------------------------
// Kernel 2: flash attention v10 (= v9 structure, relaxed launch bounds).
// grid 1024: b = bid&7 (XCD affinity), qb = bid>>3 (16 Q-rows). Block 512 =
// 8 waves; wave w owns key tiles (t*8+w)*32, t<8. Barrier-free main loop.
// K fragments direct from global (coalesced row segments); V staged in
// wave-private swizzled LDS; P de-aliased 1KB region. LDS 40960 B.
// ---------------------------------------------------------------------------
__global__ __launch_bounds__(512, 4) void flash_kernel(
    const bf16* __restrict__ wq, const bf16* __restrict__ wk,
    const bf16* __restrict__ wvt, const bf16* __restrict__ drt,
    float* __restrict__ out) {
  const int bid = blockIdx.x;
  const int b = bid & 7, qb = bid >> 3;
  const int q0 = qb * 16;
  const int tid = threadIdx.x;
  const int w = tid >> 6, lane = tid & 63, tx = tid & 15, quad = (tid >> 4) & 3;

  __shared__ __align__(16) char lds[40960];
  bf16* Vtw = (bf16*)(lds + w * 5120);         // 64 v x 32 keys (swizzled)
  bf16* Psw = (bf16*)(lds + w * 5120 + 4096);  // 16 q x 32 keys (swizzled)

  const bf16* wqb = wq + (size_t)(b * kS) * 64;
  const bf16* wkb = wk + (size_t)(b * kS) * 64;
  const bf16* wvb = wvt + b * kS;

  const int kc0 = (quad ^ (tx & 7)) * 8;        // 64-wide swizzled rows, s=0
  const int kc1 = ((4 + quad) ^ (tx & 7)) * 8;  // s=1
  const int h2 = (tx ^ (tx >> 2)) & 3;          // 32-wide rows keyed by tx

  // Q fragments: loop-invariant, direct from global
  bf16x8v aq0 = *(const bf16x8v*)&wqb[(size_t)(q0 + tx) * 64 + quad * 8];
  bf16x8v aq1 = *(const bf16x8v*)&wqb[(size_t)(q0 + tx) * 64 + 32 + quad * 8];

  f32x4 oacc[4];
#pragma unroll
  for (int nt = 0; nt < 4; ++nt) oacc[nt] = (f32x4){0.f, 0.f, 0.f, 0.f};
  float lsum[4] = {0.f, 0.f, 0.f, 0.f};

  const int vsv = lane >> 2, vsck = lane & 3;  // V staging: 4 lanes/v-row

  for (int t = 0; t < 8; ++t) {
    const int k0 = (t * 8 + w) * 32;
    // V: global -> wave-private swizzled LDS (issued first)
#pragma unroll
    for (int j = 0; j < 4; ++j) {
      int v = vsv + j * 16;
      *(uint4*)&Vtw[v * 32 + ((vsck ^ ((v ^ (v >> 2)) & 3)) * 8)] =
          *(const uint4*)&wvb[(size_t)v * kRows + k0 + vsck * 8];
    }
    // K fragments: DIRECT from global (coalesced 16x64B row segments)
    bf16x8v kb[2][2];
#pragma unroll
    for (int nt = 0; nt < 2; ++nt) {
      kb[nt][0] =
          *(const bf16x8v*)&wkb[(size_t)(k0 + nt * 16 + tx) * 64 + quad * 8];
      kb[nt][1] = *(const bf16x8v*)&wkb[(size_t)(k0 + nt * 16 + tx) * 64 + 32 +
                                        quad * 8];
    }

    // QK^T + no-max softmax numerator + swizzled P store (C -> A layout)
#pragma unroll
    for (int nt = 0; nt < 2; ++nt) {
      f32x4 z = (f32x4){0.f, 0.f, 0.f, 0.f};
      z = MFMA16(aq0, kb[nt][0], z);
      z = MFMA16(aq1, kb[nt][1], z);
#pragma unroll
      for (int r = 0; r < 4; ++r) {
        float p = __expf(z[r] * 0.1f);
        lsum[r] += p;
        int q = quad * 4 + r;
        int chunk = nt * 2 + (tx >> 3);
        Psw[q * 32 + ((chunk ^ (r ^ quad)) * 8) + (tx & 7)] = (bf16)p;
      }
    }

    // PV: O[16 q][64 v] += P[16][32] * V[32][64]
    bf16x8v pa = *(bf16x8v*)&Psw[tx * 32 + ((quad ^ h2) * 8)];
#pragma unroll
    for (int nt = 0; nt < 4; ++nt) {
      bf16x8v vb = *(bf16x8v*)&Vtw[(nt * 16 + tx) * 32 + ((quad ^ h2) * 8)];
      oacc[nt] = MFMA16(pa, vb, oacc[nt]);
    }
  }

  // ---- cross-wave combine ----
  __syncthreads();
  float* myO = (float*)(lds + w * 5120);  // 16 x 64 f32 (slot V region)
  float* Lsh = (float*)(lds + 29696);     // 8 waves x 16 rows
#pragma unroll
  for (int nt = 0; nt < 4; ++nt)
#pragma unroll
    for (int r = 0; r < 4; ++r)
      myO[(quad * 4 + r) * 64 + nt * 16 + tx] = oacc[nt][r];
#pragma unroll
  for (int r = 0; r < 4; ++r) {
    float v = lsum[r];
#pragma unroll
    for (int m = 1; m < 16; m <<= 1) v += __shfl_xor(v, m, 64);
    if (tx == 0) Lsh[w * 16 + quad * 4 + r] = v;
  }
  __syncthreads();

  // combined normalized O -> vob (bf16, row-swizzled, split across slot6/7 P)
#pragma unroll
  for (int p = 0; p < 2; ++p) {
    int e = tid + p * 512;  // 1024: 16 rows x 64 cols
    int row = e >> 6, col = e & 63;
    float s = 0.f, lt = 0.f;
#pragma unroll
    for (int wv = 0; wv < 8; ++wv) {
      s += ((const float*)(lds + wv * 5120))[e];
      lt += Lsh[wv * 16 + row];
    }
    bf16* vbase = (bf16*)(lds + ((row < 8) ? 34816 : 39936));
    vbase[(row & 7) * 64 + (((col >> 3) ^ (row & 7)) * 8) + (col & 7)] =
        (bf16)(s / lt);
  }
  __syncthreads();

  // ---- fused dense epilogue: out[16 x 512] = vob[16 x 64] @ drt^T ----
  const bf16* vbase = (const bf16*)(lds + ((tx < 8) ? 34816 : 39936)) +
                      (size_t)(tx & 7) * 64;
  bf16x8v av0 = *(const bf16x8v*)&vbase[kc0];
  bf16x8v av1 = *(const bf16x8v*)&vbase[kc1];

  float* OutS = (float*)lds;  // 16 x 260 f32 = 16640 B (dead slots 0-3)
#pragma unroll
  for (int c = 0; c < 2; ++c) {  // two 256-col chunks
    if (c) __syncthreads();      // prior chunk's OutS reads done
#pragma unroll
    for (int i = 0; i < 2; ++i) {
      const int ct = c * 16 + w * 2 + i;  // global 16-col tile
      bf16x8v bd0 =
          *(const bf16x8v*)&drt[(size_t)(ct * 16 + tx) * 64 + quad * 8];
      bf16x8v bd1 =
          *(const bf16x8v*)&drt[(size_t)(ct * 16 + tx) * 64 + 32 + quad * 8];
      f32x4 z = (f32x4){0.f, 0.f, 0.f, 0.f};
      z = MFMA16(av0, bd0, z);
      z = MFMA16(av1, bd1, z);
#pragma unroll
      for (int r = 0; r < 4; ++r)
        OutS[(quad * 4 + r) * 260 + (w * 2 + i) * 16 + tx] = z[r];
    }
    __syncthreads();
    // coalesced full-row stores: 16 rows x 256 f32 = 1KB contiguous per row
#pragma unroll
    for (int p = 0; p < 2; ++p) {
      int e = tid + p * 512;  // 1024 float4: 16 rows x 64 segs
      int row = e >> 6, seg = e & 63;
      *(float4*)&out[(size_t)(b * kS + q0 + row) * kD + c * 256 + seg * 4] =
          *(float4*)&OutS[row * 260 + seg * 4];
    }
  }
}

extern "C" void kernel_launch(void* const* d_in, const int* in_sizes, int n_in,
                              void* d_out, int out_size, void* d_ws,
                              size_t ws_size, hipStream_t stream) {
  const float* x = (const float*)d_in[0];      // [8,2048,512]
  const float* w = (const float*)d_in[1];      // [3,512,64]
  const float* dense = (const float*)d_in[2];  // [512,512]
  float* out = (float*)d_out;                  // [8,2048,512] fp32

  bf16* wq = (bf16*)d_ws;                // 1,048,576 bf16
  bf16* wk = wq + (size_t)kRows * 64;    // 1,048,576
  bf16* wvt = wk + (size_t)kRows * 64;   // 1,048,576  [64][16384]
  bf16* wtg = wvt + (size_t)kRows * 64;  // 98,304     [3][64][512]
  bf16* drt = wtg + 98304;               // 32,768     [512][64]

  prep_kernel<<<512, 256, 0, stream>>>(w, dense, wtg, drt);
  proj_kernel<<<256, 256, 0, stream>>>(x, wtg, wq, wk, wvt);
  flash_kernel<<<1024, 512, 0, stream>>>(wq, wk, wvt, drt, out);
}

// Round 11
// 138.567 us; speedup vs baseline: 1.1038x; 1.0772x over previous
//
#include <hip/hip_runtime.h>
#include <math.h>

// MultiHeadAttention_3728031613617 — bf16-MFMA pipeline v11 (= v8 verbatim).
// v8 measured best: 138.3 µs total, flash 45.4 µs. r9/r10 proved the
// Q16/K-direct line inferior (57-61 µs) even with spill fixed; reverting.
// Flash: Q-tile 32, block 512 (8-wave K-split), wave-private 8KB LDS slots
// (K 4KB [P aliases first 2KB], V 4KB), XOR swizzle (r5-verified), fused
// dense tail with LDS-staged coalesced full-row stores (r8 WRITE-verified).

typedef __bf16 bf16;
typedef __bf16 bf16x4v __attribute__((ext_vector_type(4)));
typedef __bf16 bf16x8v __attribute__((ext_vector_type(8)));
typedef float f32x4 __attribute__((ext_vector_type(4)));

namespace {
constexpr int kS = 2048;
constexpr int kD = 512;
constexpr int kRows = 16384;  // 8 * 2048
}

#define MFMA16(a, b, c) __builtin_amdgcn_mfma_f32_16x16x32_bf16((a), (b), (c), 0, 0, 0)

// ---------------------------------------------------------------------------
// Kernel 0: prep. wtg[mat][n=64][k=512] = (bf16)W[mat][k][n]
//           drt[o=512][j=64] = (bf16) sum_h dense[h*64+j, o]  (for B-frags)
// ---------------------------------------------------------------------------
__global__ __launch_bounds__(256) void prep_kernel(const float* __restrict__ w,
                                                   const float* __restrict__ dense,
                                                   bf16* __restrict__ wtg,
                                                   bf16* __restrict__ drt) {
  int idx = blockIdx.x * 256 + threadIdx.x;  // < 131072
  if (idx < 98304) {
    int mat = idx >> 15, rem = idx & 32767;
    int n = rem >> 9, k = rem & 511;
    wtg[idx] = (bf16)w[mat * 32768 + k * 64 + n];
  } else {
    int e = idx - 98304;  // < 32768
    int o = e >> 6, j = e & 63;
    float s = 0.f;
#pragma unroll
    for (int h = 0; h < 8; ++h) s += dense[(size_t)(h * 64 + j) * kD + o];
    drt[e] = (bf16)s;  // [o][j]
  }
}

// ---------------------------------------------------------------------------
// Kernel 1: fused QKV projection (x read ONCE). grid 256, block 256. (v6)
// ---------------------------------------------------------------------------
__global__ __launch_bounds__(256) void proj_kernel(const float* __restrict__ x,
                                                   const bf16* __restrict__ wtg,
                                                   bf16* __restrict__ wq,
                                                   bf16* __restrict__ wk,
                                                   bf16* __restrict__ wvt) {
  const int bt = blockIdx.x;
  const int tid = threadIdx.x;
  const int w = tid >> 6, tx = tid & 15, quad = (tid >> 4) & 3;
  const int row0 = bt * 64;

  __shared__ bf16 Xs[64 * 72];
  __shared__ bf16 Wts[3 * 64 * 72];

  f32x4 acc[3][4];
#pragma unroll
  for (int m = 0; m < 3; ++m)
#pragma unroll
    for (int nt = 0; nt < 4; ++nt) acc[m][nt] = (f32x4){0.f, 0.f, 0.f, 0.f};

  for (int k0 = 0; k0 < kD; k0 += 64) {
    __syncthreads();
#pragma unroll
    for (int p = 0; p < 4; ++p) {
      int i4 = tid + p * 256;
      int r = i4 >> 4, c4 = (i4 & 15) * 4;
      float4 f = *(const float4*)&x[(size_t)(row0 + r) * kD + k0 + c4];
      bf16x4v h = {(bf16)f.x, (bf16)f.y, (bf16)f.z, (bf16)f.w};
      *(bf16x4v*)&Xs[r * 72 + c4] = h;
    }
#pragma unroll
    for (int p = 0; p < 6; ++p) {
      int cc = tid + p * 256;
      int mat = cc >> 9, rem = cc & 511;
      int n = rem >> 3, c8 = (rem & 7) * 8;
      *(uint4*)&Wts[(mat * 64 + n) * 72 + c8] =
          *(const uint4*)&wtg[(size_t)mat * 32768 + (size_t)n * 512 + k0 + c8];
    }
    __syncthreads();
#pragma unroll
    for (int s = 0; s < 2; ++s) {
      bf16x8v a = *(bf16x8v*)&Xs[(w * 16 + tx) * 72 + s * 32 + quad * 8];
#pragma unroll
      for (int m = 0; m < 3; ++m)
#pragma unroll
        for (int nt = 0; nt < 4; ++nt) {
          bf16x8v bfr =
              *(bf16x8v*)&Wts[(m * 64 + nt * 16 + tx) * 72 + s * 32 + quad * 8];
          acc[m][nt] = MFMA16(a, bfr, acc[m][nt]);
        }
    }
  }

#pragma unroll
  for (int nt = 0; nt < 4; ++nt)
#pragma unroll
    for (int r = 0; r < 4; ++r) {
      int row_g = row0 + w * 16 + quad * 4 + r;
      int col = nt * 16 + tx;
      wq[(size_t)row_g * 64 + col] = (bf16)acc[0][nt][r];
      wk[(size_t)row_g * 64 + col] = (bf16)acc[1][nt][r];
    }
  __syncthreads();
  bf16* Vt = Xs;
#pragma unroll
  for (int nt = 0; nt < 4; ++nt)
#pragma unroll
    for (int r = 0; r < 4; ++r)
      Vt[(nt * 16 + tx) * 72 + (w * 16 + quad * 4 + r)] = (bf16)acc[2][nt][r];
  __syncthreads();
#pragma unroll
  for (int p = 0; p < 2; ++p) {
    int c = tid + p * 256;
    int v = c >> 3, seg = c & 7;
    *(uint4*)&wvt[(size_t)v * kRows + row0 + seg * 8] =
        *(uint4*)&Vt[v * 72 + seg * 8];
  }
}

// ---------------------------------------------------------------------------
// Kernel 2: flash attention (v8) — Q-tile 32, fused coalesced dense tail.
// grid 512: b = bid&7, qb = bid>>3 (32 Q-rows). Block 512 = 8 waves; wave w
// owns key tiles (t*8+w)*32, t<8. Barrier-free main loop, wave-private 8KB
// slots (P aliases K), XOR swizzle. Tail: combine -> vob bf16 -> dense MFMA
// vs drt -> LDS-staged 32x256 f32 chunks -> full-row float4 stores to out.
// LDS: 64KB slots (reused as OutS) + 1KB Lsh + 4KB vob = 70656 B -> 2 blk/CU.
// ---------------------------------------------------------------------------
__global__ __launch_bounds__(512, 4) void flash_kernel(
    const bf16* __restrict__ wq, const bf16* __restrict__ wk,
    const bf16* __restrict__ wvt, const bf16* __restrict__ drt,
    float* __restrict__ out) {
  const int bid = blockIdx.x;
  const int b = bid & 7, qb = bid >> 3;
  const int q0 = qb * 32;
  const int tid = threadIdx.x;
  const int w = tid >> 6, lane = tid & 63, tx = tid & 15, quad = (tid >> 4) & 3;

  __shared__ __align__(16) char lds[65536];   // 8 waves x 8KB slots
  __shared__ float Lsh[256];                  // 8 waves x 32 rows
  __shared__ __align__(16) bf16 vob[32 * 64]; // combined O, swizzled rows
  bf16* Ksw = (bf16*)(lds + w * 8192);        // 32 keys x 64 c (swizzled)
  bf16* Psw = Ksw;                            // 32 q x 32 k, aliases K[0:16]
  bf16* Vtw = (bf16*)(lds + w * 8192 + 4096); // 64 v x 32 keys (swizzled)

  const bf16* wqb = wq + (size_t)(b * kS) * 64;
  const bf16* wkb = wk + (size_t)(b * kS) * 64;
  const bf16* wvb = wvt + b * kS;

  const int kc0 = (quad ^ (tx & 7)) * 8;        // 64-wide rows, s=0 chunk
  const int kc1 = ((4 + quad) ^ (tx & 7)) * 8;  // s=1 chunk
  const int h2 = (tx ^ (tx >> 2)) & 3;          // 32-wide rows keyed by tx

  // Q fragments: loop-invariant, direct from global (one-time cost)
  bf16x8v aq[2][2];
#pragma unroll
  for (int rt = 0; rt < 2; ++rt)
#pragma unroll
    for (int s = 0; s < 2; ++s)
      aq[rt][s] = *(const bf16x8v*)&wqb[(size_t)(q0 + rt * 16 + tx) * 64 +
                                        s * 32 + quad * 8];

  f32x4 oacc[2][4];
#pragma unroll
  for (int rt = 0; rt < 2; ++rt)
#pragma unroll
    for (int nt = 0; nt < 4; ++nt) oacc[rt][nt] = (f32x4){0.f, 0.f, 0.f, 0.f};
  float lsum[2][4] = {};

  const int ksr = lane >> 3, kslc = lane & 7;  // K staging: 8 lanes/row
  const int vsv = lane >> 2, vsck = lane & 3;  // V staging: 4 lanes/v-row

  for (int t = 0; t < 8; ++t) {
    const int k0 = (t * 8 + w) * 32;
#pragma unroll
    for (int j = 0; j < 4; ++j) {
      int r = ksr + j * 8;
      *(uint4*)&Ksw[r * 64 + ((kslc ^ (r & 7)) * 8)] =
          *(const uint4*)&wkb[(size_t)(k0 + r) * 64 + kslc * 8];
      int v = vsv + j * 16;
      *(uint4*)&Vtw[v * 32 + ((vsck ^ ((v ^ (v >> 2)) & 3)) * 8)] =
          *(const uint4*)&wvb[(size_t)v * kRows + k0 + vsck * 8];
    }

    // QK^T + no-max softmax numerator + swizzled P store (C -> A layout)
#pragma unroll
    for (int nt = 0; nt < 2; ++nt) {
      int krow = nt * 16 + tx;
      bf16x8v b0 = *(bf16x8v*)&Ksw[krow * 64 + kc0];
      bf16x8v b1 = *(bf16x8v*)&Ksw[krow * 64 + kc1];
#pragma unroll
      for (int rt = 0; rt < 2; ++rt) {
        f32x4 z = (f32x4){0.f, 0.f, 0.f, 0.f};
        z = MFMA16(aq[rt][0], b0, z);
        z = MFMA16(aq[rt][1], b1, z);
#pragma unroll
        for (int r = 0; r < 4; ++r) {
          float p = __expf(z[r] * 0.1f);
          lsum[rt][r] += p;
          int q = rt * 16 + quad * 4 + r;
          int chunk = nt * 2 + (tx >> 3);
          Psw[q * 32 + ((chunk ^ (r ^ quad)) * 8) + (tx & 7)] = (bf16)p;
        }
      }
    }

    // PV: O[32 q][64 v] += P[32][32] * V[32][64]
#pragma unroll
    for (int rt = 0; rt < 2; ++rt) {
      bf16x8v pa = *(bf16x8v*)&Psw[(rt * 16 + tx) * 32 + ((quad ^ h2) * 8)];
#pragma unroll
      for (int nt = 0; nt < 4; ++nt) {
        bf16x8v vb = *(bf16x8v*)&Vtw[(nt * 16 + tx) * 32 + ((quad ^ h2) * 8)];
        oacc[rt][nt] = MFMA16(pa, vb, oacc[rt][nt]);
      }
    }
  }

  // ---- cross-wave combine (private 8KB f32 regions, no atomics) ----
  __syncthreads();
  float* myO = (float*)(lds + w * 8192);  // 32 x 64 f32 (exactly 8KB)
  float* myL = Lsh + w * 32;
#pragma unroll
  for (int rt = 0; rt < 2; ++rt)
#pragma unroll
    for (int nt = 0; nt < 4; ++nt)
#pragma unroll
      for (int r = 0; r < 4; ++r)
        myO[(rt * 16 + quad * 4 + r) * 64 + nt * 16 + tx] = oacc[rt][nt][r];
#pragma unroll
  for (int rt = 0; rt < 2; ++rt)
#pragma unroll
    for (int r = 0; r < 4; ++r) {
      float v = lsum[rt][r];
#pragma unroll
      for (int m = 1; m < 16; m <<= 1) v += __shfl_xor(v, m, 64);
      if (tx == 0) myL[rt * 16 + quad * 4 + r] = v;
    }
  __syncthreads();

  // combined, normalized O -> vob (bf16, row-swizzled for A-frag reads)
#pragma unroll
  for (int p = 0; p < 4; ++p) {
    int e = tid + p * 512;  // 2048: 32 rows x 64 cols
    int row = e >> 6, col = e & 63;
    float s = 0.f, lt = 0.f;
#pragma unroll
    for (int wv = 0; wv < 8; ++wv) {
      s += ((const float*)(lds + wv * 8192))[e];
      lt += Lsh[wv * 32 + row];
    }
    vob[row * 64 + (((col >> 3) ^ (row & 7)) * 8) + (col & 7)] = (bf16)(s / lt);
  }
  __syncthreads();

  // ---- fused dense epilogue: out[32 x 512] = vob[32 x 64] @ drt^T ----
  bf16x8v av[2][2];
#pragma unroll
  for (int rt = 0; rt < 2; ++rt) {
    av[rt][0] = *(bf16x8v*)&vob[(rt * 16 + tx) * 64 + kc0];
    av[rt][1] = *(bf16x8v*)&vob[(rt * 16 + tx) * 64 + kc1];
  }

  float* OutS = (float*)lds;  // 32 x 260 f32 = 33280 B (aliases dead slots)
#pragma unroll
  for (int c = 0; c < 2; ++c) {  // two 256-col chunks
    if (c) __syncthreads();      // prior chunk's LDS reads done
#pragma unroll
    for (int i = 0; i < 2; ++i) {
      const int ct = c * 16 + w * 2 + i;  // global 16-col tile
      bf16x8v bd0 =
          *(const bf16x8v*)&drt[(size_t)(ct * 16 + tx) * 64 + quad * 8];
      bf16x8v bd1 =
          *(const bf16x8v*)&drt[(size_t)(ct * 16 + tx) * 64 + 32 + quad * 8];
#pragma unroll
      for (int rt = 0; rt < 2; ++rt) {
        f32x4 z = (f32x4){0.f, 0.f, 0.f, 0.f};
        z = MFMA16(av[rt][0], bd0, z);
        z = MFMA16(av[rt][1], bd1, z);
#pragma unroll
        for (int r = 0; r < 4; ++r)
          OutS[(rt * 16 + quad * 4 + r) * 260 + (w * 2 + i) * 16 + tx] = z[r];
      }
    }
    __syncthreads();
    // coalesced full-row stores: 32 rows x 256 f32 = 1KB contiguous per row
#pragma unroll
    for (int p = 0; p < 4; ++p) {
      int e = tid + p * 512;  // 2048 float4
      int row = e >> 6, seg = e & 63;
      *(float4*)&out[(size_t)(b * kS + q0 + row) * kD + c * 256 + seg * 4] =
          *(float4*)&OutS[row * 260 + seg * 4];
    }
  }
}

extern "C" void kernel_launch(void* const* d_in, const int* in_sizes, int n_in,
                              void* d_out, int out_size, void* d_ws,
                              size_t ws_size, hipStream_t stream) {
  const float* x = (const float*)d_in[0];      // [8,2048,512]
  const float* w = (const float*)d_in[1];      // [3,512,64]
  const float* dense = (const float*)d_in[2];  // [512,512]
  float* out = (float*)d_out;                  // [8,2048,512] fp32

  bf16* wq = (bf16*)d_ws;                // 1,048,576 bf16
  bf16* wk = wq + (size_t)kRows * 64;    // 1,048,576
  bf16* wvt = wk + (size_t)kRows * 64;   // 1,048,576  [64][16384]
  bf16* wtg = wvt + (size_t)kRows * 64;  // 98,304     [3][64][512]
  bf16* drt = wtg + 98304;               // 32,768     [512][64]

  prep_kernel<<<512, 256, 0, stream>>>(w, dense, wtg, drt);
  proj_kernel<<<256, 256, 0, stream>>>(x, wtg, wq, wk, wvt);
  flash_kernel<<<512, 512, 0, stream>>>(wq, wk, wvt, drt, out);
}